// Round 1
// baseline (1169.353 us; speedup 1.0000x reference)
//
#include <hip/hip_runtime.h>
#include <math.h>

#define B_ 128
#define S_ 1024
#define D_ 512
#define H_ 512

// ---------------------------------------------------------------------------
// zero-fill (ws is poisoned 0xAA before every timed launch)
__global__ void zero_k(float* __restrict__ p, int n) {
    int i = blockIdx.x * 256 + threadIdx.x;
    if (i < n) p[i] = 0.f;
}

// ---------------------------------------------------------------------------
// out[b,h] = dot(X[b,:], W[h,:]) + bias[h]   (X:[B,D], W:[H,D], D=512)
__global__ __launch_bounds__(256) void linear_k(const float* __restrict__ X,
                                                const float* __restrict__ W,
                                                const float* __restrict__ bias,
                                                float* __restrict__ out) {
    int idx = blockIdx.x * 256 + threadIdx.x;
    int b = idx >> 9;          // /512
    int h = idx & 511;
    const float4* x = (const float4*)(X + (size_t)b * D_);
    const float4* w = (const float4*)(W + (size_t)h * D_);
    float s = 0.f;
#pragma unroll 8
    for (int k = 0; k < D_ / 4; ++k) {
        float4 xv = x[k], wv = w[k];
        s = fmaf(xv.x, wv.x, s);
        s = fmaf(xv.y, wv.y, s);
        s = fmaf(xv.z, wv.z, s);
        s = fmaf(xv.w, wv.w, s);
    }
    out[idx] = s + bias[h];
}

// ---------------------------------------------------------------------------
// Big fused GEMM: per (b, h-tile, s-tile) compute 128x128 tile of
//   ctx[b,h,s] = W_ctx[h,:]·context[b,s,:]
// then epilogue: partial att[b,s] += sum_h V[h]*tanh(inp[b,h]+b_ctx[h]+ctx)
// h-tiles accumulate via atomicAdd (att pre-zeroed).
__global__ __launch_bounds__(256) void score_gemm(const float* __restrict__ ctx,
                                                  const float* __restrict__ Wc,
                                                  const float* __restrict__ bc,
                                                  const float* __restrict__ Vv,
                                                  const float* __restrict__ inp,
                                                  float* __restrict__ att) {
    __shared__ float As[16][128];   // [k][h]  (k-major so fragment reads are b128)
    __shared__ float Bs[16][128];   // [k][s]
    __shared__ float red[16][128];  // h-group reduction

    const int tid = threadIdx.x;
    const int h0 = blockIdx.x * 128;   // hblk fastest -> siblings share context tile
    const int s0 = blockIdx.y * 128;
    const int b = blockIdx.z;

    const int rg = tid >> 4;   // 0..15 row(h) group
    const int cg = tid & 15;   // 0..15 col(s) group

    const int lr = tid & 127;  // staging row
    const int lkq = tid >> 7;  // 0..1 which 8-k half

    const float* Ag = Wc + (size_t)(h0 + lr) * D_ + lkq * 8;
    const float* Bg = ctx + ((size_t)b * S_ + (s0 + lr)) * D_ + lkq * 8;

    float acc[8][8];
#pragma unroll
    for (int i = 0; i < 8; ++i)
#pragma unroll
        for (int j = 0; j < 8; ++j) acc[i][j] = 0.f;

    for (int k0 = 0; k0 < D_; k0 += 16) {
        float4 a0 = *(const float4*)(Ag + k0);
        float4 a1 = *(const float4*)(Ag + k0 + 4);
        float4 b0 = *(const float4*)(Bg + k0);
        float4 b1 = *(const float4*)(Bg + k0 + 4);
        __syncthreads();   // previous iteration's reads complete
        const int kb = lkq * 8;
        As[kb + 0][lr] = a0.x; As[kb + 1][lr] = a0.y;
        As[kb + 2][lr] = a0.z; As[kb + 3][lr] = a0.w;
        As[kb + 4][lr] = a1.x; As[kb + 5][lr] = a1.y;
        As[kb + 6][lr] = a1.z; As[kb + 7][lr] = a1.w;
        Bs[kb + 0][lr] = b0.x; Bs[kb + 1][lr] = b0.y;
        Bs[kb + 2][lr] = b0.z; Bs[kb + 3][lr] = b0.w;
        Bs[kb + 4][lr] = b1.x; Bs[kb + 5][lr] = b1.y;
        Bs[kb + 6][lr] = b1.z; Bs[kb + 7][lr] = b1.w;
        __syncthreads();
#pragma unroll
        for (int kk = 0; kk < 16; ++kk) {
            float a[8], bb[8];
            *(float4*)(a) = *(const float4*)(&As[kk][rg * 8]);
            *(float4*)(a + 4) = *(const float4*)(&As[kk][rg * 8 + 4]);
            *(float4*)(bb) = *(const float4*)(&Bs[kk][cg * 8]);
            *(float4*)(bb + 4) = *(const float4*)(&Bs[kk][cg * 8 + 4]);
#pragma unroll
            for (int i = 0; i < 8; ++i)
#pragma unroll
                for (int j = 0; j < 8; ++j)
                    acc[i][j] = fmaf(a[i], bb[j], acc[i][j]);
        }
    }

    // epilogue: score = V[h]*tanh(inp[b,h]+b_ctx[h]+acc), reduce over h
    float ch[8], vh[8];
#pragma unroll
    for (int i = 0; i < 8; ++i) {
        int h = h0 + rg * 8 + i;
        ch[i] = inp[(size_t)b * H_ + h] + bc[h];
        vh[i] = Vv[h];
    }
    float p[8];
#pragma unroll
    for (int j = 0; j < 8; ++j) {
        float s = 0.f;
#pragma unroll
        for (int i = 0; i < 8; ++i) s = fmaf(vh[i], tanhf(ch[i] + acc[i][j]), s);
        p[j] = s;
    }
#pragma unroll
    for (int j = 0; j < 8; ++j) red[rg][cg * 8 + j] = p[j];
    __syncthreads();
    if (tid < 128) {
        float s = 0.f;
#pragma unroll
        for (int g = 0; g < 16; ++g) s += red[g][tid];
        atomicAdd(att + (size_t)b * S_ + s0 + tid, s);
    }
}

// ---------------------------------------------------------------------------
// masked softmax over S per batch row; mask!=0 -> -inf
__global__ __launch_bounds__(256) void softmax_k(const float* __restrict__ att,
                                                 const int* __restrict__ mask,
                                                 float* __restrict__ alpha) {
    const int b = blockIdx.x;
    const int t = threadIdx.x;
    __shared__ float sm[256];
    float v[4];
    float mx = -INFINITY;
#pragma unroll
    for (int i = 0; i < 4; ++i) {
        int s = t + i * 256;
        float a = att[(size_t)b * S_ + s];
        int mk = mask[(size_t)b * S_ + s];
        v[i] = mk ? -INFINITY : a;
        mx = fmaxf(mx, v[i]);
    }
    sm[t] = mx;
    __syncthreads();
    for (int off = 128; off > 0; off >>= 1) {
        if (t < off) sm[t] = fmaxf(sm[t], sm[t + off]);
        __syncthreads();
    }
    mx = sm[0];
    __syncthreads();
    float e[4];
    float sum = 0.f;
#pragma unroll
    for (int i = 0; i < 4; ++i) {
        e[i] = expf(v[i] - mx);
        sum += e[i];
    }
    sm[t] = sum;
    __syncthreads();
    for (int off = 128; off > 0; off >>= 1) {
        if (t < off) sm[t] += sm[t + off];
        __syncthreads();
    }
    float inv = 1.f / sm[0];
#pragma unroll
    for (int i = 0; i < 4; ++i) alpha[(size_t)b * S_ + t + i * 256] = e[i] * inv;
}

// ---------------------------------------------------------------------------
// cbar[b,:] += sum_{s in chunk} alpha[b,s] * context[b,s,:]   (cbar pre-zeroed)
__global__ __launch_bounds__(256) void cbar_k(const float* __restrict__ ctx,
                                              const float* __restrict__ alpha,
                                              float* __restrict__ cbar) {
    const int b = blockIdx.y;
    const int s0 = blockIdx.x * 128;
    const int t = threadIdx.x;
    __shared__ float al[128];
    if (t < 128) al[t] = alpha[(size_t)b * S_ + s0 + t];
    __syncthreads();
    const float2* base = (const float2*)(ctx + ((size_t)b * S_ + s0) * D_);
    float2 c = {0.f, 0.f};
    for (int s = 0; s < 128; ++s) {
        float a = al[s];
        float2 x = base[(size_t)s * (D_ / 2) + t];
        c.x = fmaf(a, x.x, c.x);
        c.y = fmaf(a, x.y, c.y);
    }
    atomicAdd(cbar + (size_t)b * D_ + 2 * t, c.x);
    atomicAdd(cbar + (size_t)b * D_ + 2 * t + 1, c.y);
}

// ---------------------------------------------------------------------------
extern "C" void kernel_launch(void* const* d_in, const int* in_sizes, int n_in,
                              void* d_out, int out_size, void* d_ws, size_t ws_size,
                              hipStream_t stream) {
    const float* input = (const float*)d_in[0];   // [B,D]
    const float* ctx   = (const float*)d_in[1];   // [B,S,D]
    const int*   mask  = (const int*)d_in[2];     // [B,S]
    const float* W_in  = (const float*)d_in[3];   // [H,D]
    const float* b_in  = (const float*)d_in[4];   // [H]
    const float* W_ctx = (const float*)d_in[5];   // [H,D]
    const float* b_ctx = (const float*)d_in[6];   // [H]
    const float* V     = (const float*)d_in[7];   // [H]

    float* hidden = (float*)d_out;                // [B,H]
    float* alpha  = (float*)d_out + B_ * H_;      // [B,S]

    float* inp  = (float*)d_ws;                   // B*H
    float* att  = inp + B_ * H_;                  // B*S
    float* cbar = att + B_ * S_;                  // B*D  (att+cbar contiguous)

    int nz = B_ * S_ + B_ * D_;
    zero_k<<<(nz + 255) / 256, 256, 0, stream>>>(att, nz);

    linear_k<<<(B_ * H_) / 256, 256, 0, stream>>>(input, W_in, b_in, inp);

    dim3 g2(H_ / 128, S_ / 128, B_);              // hblk fastest for L2/L3 reuse
    score_gemm<<<g2, 256, 0, stream>>>(ctx, W_ctx, b_ctx, V, inp, att);

    softmax_k<<<B_, 256, 0, stream>>>(att, mask, alpha);

    dim3 g4(S_ / 128, B_);
    cbar_k<<<g4, 256, 0, stream>>>(ctx, alpha, cbar);

    linear_k<<<(B_ * H_) / 256, 256, 0, stream>>>(cbar, W_ctx, b_ctx, hidden);
}

// Round 2
// 624.481 us; speedup vs baseline: 1.8725x; 1.8725x over previous
//
#include <hip/hip_runtime.h>
#include <math.h>

#define B_ 128
#define S_ 1024
#define D_ 512
#define H_ 512

typedef __bf16 bf16x4 __attribute__((ext_vector_type(4)));
typedef __bf16 bf16x8 __attribute__((ext_vector_type(8)));
typedef float  f32x4  __attribute__((ext_vector_type(4)));

// ---------------------------------------------------------------------------
__global__ void zero_k(float* __restrict__ p, int n) {
    int i = blockIdx.x * 256 + threadIdx.x;
    if (i < n) p[i] = 0.f;
}

// ---------------------------------------------------------------------------
// out[b,h] = dot(X[b,:], W[h,:]) + bias[h]   (X:[B,D], W:[H,D], D=512)
__global__ __launch_bounds__(256) void linear_k(const float* __restrict__ X,
                                                const float* __restrict__ W,
                                                const float* __restrict__ bias,
                                                float* __restrict__ out) {
    int idx = blockIdx.x * 256 + threadIdx.x;
    int b = idx >> 9;
    int h = idx & 511;
    const float4* x = (const float4*)(X + (size_t)b * D_);
    const float4* w = (const float4*)(W + (size_t)h * D_);
    float s = 0.f;
#pragma unroll 8
    for (int k = 0; k < D_ / 4; ++k) {
        float4 xv = x[k], wv = w[k];
        s = fmaf(xv.x, wv.x, s);
        s = fmaf(xv.y, wv.y, s);
        s = fmaf(xv.z, wv.z, s);
        s = fmaf(xv.w, wv.w, s);
    }
    out[idx] = s + bias[h];
}

// ---------------------------------------------------------------------------
__device__ inline void split4(float4 v, bf16x4& hi, bf16x4& lo) {
    hi[0] = (__bf16)v.x; lo[0] = (__bf16)(v.x - (float)hi[0]);
    hi[1] = (__bf16)v.y; lo[1] = (__bf16)(v.y - (float)hi[1]);
    hi[2] = (__bf16)v.z; lo[2] = (__bf16)(v.z - (float)hi[2]);
    hi[3] = (__bf16)v.w; lo[3] = (__bf16)(v.w - (float)hi[3]);
}

// fast tanh: 1 - 2/(e^{2x}+1); exact limits at +/-inf, err ~1e-6
__device__ inline float fast_tanh(float x) {
    float e = __expf(2.f * x);
    return 1.f - 2.f / (e + 1.f);
}

// ---------------------------------------------------------------------------
// Score GEMM via bf16 hi/lo split MFMA (3-term fp32 emulation).
// Per (h-blk, s-blk, b): 128x128 tile of ctxp[h,s] = W_ctx[h,:]·context[b,s,:]
// Epilogue: att[b,s] += sum_h V[h]*tanh(inp[b,h]+b_ctx[h]+ctxp)  (atomicAdd)
__global__ __launch_bounds__(256) void score_mfma(const float* __restrict__ ctx,
                                                  const float* __restrict__ Wc,
                                                  const float* __restrict__ bc,
                                                  const float* __restrict__ Vv,
                                                  const float* __restrict__ inp,
                                                  float* __restrict__ att) {
    // row-major [row][k] tiles, stride 40 bf16 = 80 B -> 16B-aligned b128 frags
    __shared__ __align__(16) __bf16 Ah[128][40];
    __shared__ __align__(16) __bf16 Al[128][40];
    __shared__ __align__(16) __bf16 Bh[128][40];
    __shared__ __align__(16) __bf16 Bl[128][40];
    __shared__ float red[8][128];

    const int tid = threadIdx.x;
    const int h0 = blockIdx.x * 128;   // h-blk fastest: 4 h-blks share ctx tile in L2
    const int s0 = blockIdx.y * 128;
    const int b  = blockIdx.z;

    // staging: thread covers rows rb+{0,32,64,96}, float4-group grp
    const int rb  = tid >> 3;   // 0..31
    const int grp = tid & 7;    // 0..7 -> k-cols grp*4..grp*4+3

    const int wave = tid >> 6;
    const int lane = tid & 63;
    const int wm = wave >> 1, wn = wave & 1;   // 2x2 wave grid (h x s)
    const int l15 = lane & 15, quad = lane >> 4;

    const float* Abase = Wc  + (size_t)(h0 + rb) * D_ + grp * 4;
    const float* Bbase = ctx + ((size_t)b * S_ + s0 + rb) * D_ + grp * 4;

    f32x4 acc[4][4];
#pragma unroll
    for (int mi = 0; mi < 4; ++mi)
#pragma unroll
        for (int ni = 0; ni < 4; ++ni) acc[mi][ni] = (f32x4){0.f, 0.f, 0.f, 0.f};

    float4 ra[4], rbv[4];
#pragma unroll
    for (int i = 0; i < 4; ++i) {
        ra[i]  = *(const float4*)(Abase + (size_t)(32 * i) * D_);
        rbv[i] = *(const float4*)(Bbase + (size_t)(32 * i) * D_);
    }

    for (int k0 = 0; k0 < D_; k0 += 32) {
        __syncthreads();   // previous iteration's fragment reads complete
#pragma unroll
        for (int i = 0; i < 4; ++i) {
            const int row = rb + 32 * i;
            bf16x4 hi, lo;
            split4(ra[i], hi, lo);
            *(bf16x4*)&Ah[row][grp * 4] = hi;
            *(bf16x4*)&Al[row][grp * 4] = lo;
            split4(rbv[i], hi, lo);
            *(bf16x4*)&Bh[row][grp * 4] = hi;
            *(bf16x4*)&Bl[row][grp * 4] = lo;
        }
        __syncthreads();
        if (k0 + 32 < D_) {
#pragma unroll
            for (int i = 0; i < 4; ++i) {
                ra[i]  = *(const float4*)(Abase + (size_t)(32 * i) * D_ + k0 + 32);
                rbv[i] = *(const float4*)(Bbase + (size_t)(32 * i) * D_ + k0 + 32);
            }
        }
        // fragments: A[m=l15][k=quad*8+j], B[k=quad*8+j][n=l15]
        bf16x8 bhf[4], blf[4];
#pragma unroll
        for (int ni = 0; ni < 4; ++ni) {
            const int r = wn * 64 + ni * 16 + l15;
            bhf[ni] = *(const bf16x8*)&Bh[r][quad * 8];
            blf[ni] = *(const bf16x8*)&Bl[r][quad * 8];
        }
#pragma unroll
        for (int mi = 0; mi < 4; ++mi) {
            const int r = wm * 64 + mi * 16 + l15;
            bf16x8 ah = *(const bf16x8*)&Ah[r][quad * 8];
            bf16x8 al = *(const bf16x8*)&Al[r][quad * 8];
#pragma unroll
            for (int ni = 0; ni < 4; ++ni) {
                acc[mi][ni] = __builtin_amdgcn_mfma_f32_16x16x32_bf16(ah, bhf[ni], acc[mi][ni], 0, 0, 0);
                acc[mi][ni] = __builtin_amdgcn_mfma_f32_16x16x32_bf16(ah, blf[ni], acc[mi][ni], 0, 0, 0);
                acc[mi][ni] = __builtin_amdgcn_mfma_f32_16x16x32_bf16(al, bhf[ni], acc[mi][ni], 0, 0, 0);
            }
        }
    }

    // epilogue: C/D layout col=l15 (s), row=quad*4+reg (h)
    float p[4] = {0.f, 0.f, 0.f, 0.f};
#pragma unroll
    for (int mi = 0; mi < 4; ++mi) {
#pragma unroll
        for (int r = 0; r < 4; ++r) {
            const int h = h0 + wm * 64 + mi * 16 + quad * 4 + r;
            const float c  = inp[(size_t)b * H_ + h] + bc[h];
            const float vh = Vv[h];
#pragma unroll
            for (int ni = 0; ni < 4; ++ni)
                p[ni] = fmaf(vh, fast_tanh(c + acc[mi][ni][r]), p[ni]);
        }
    }
    const int cid = wm * 4 + quad;   // 8 h-contributors per s column
#pragma unroll
    for (int ni = 0; ni < 4; ++ni)
        red[cid][wn * 64 + ni * 16 + l15] = p[ni];
    __syncthreads();
    if (tid < 128) {
        float s = 0.f;
#pragma unroll
        for (int g = 0; g < 8; ++g) s += red[g][tid];
        atomicAdd(att + (size_t)b * S_ + s0 + tid, s);
    }
}

// ---------------------------------------------------------------------------
__global__ __launch_bounds__(256) void softmax_k(const float* __restrict__ att,
                                                 const int* __restrict__ mask,
                                                 float* __restrict__ alpha) {
    const int b = blockIdx.x;
    const int t = threadIdx.x;
    __shared__ float sm[256];
    float v[4];
    float mx = -INFINITY;
#pragma unroll
    for (int i = 0; i < 4; ++i) {
        int s = t + i * 256;
        float a = att[(size_t)b * S_ + s];
        int mk = mask[(size_t)b * S_ + s];
        v[i] = mk ? -INFINITY : a;
        mx = fmaxf(mx, v[i]);
    }
    sm[t] = mx;
    __syncthreads();
    for (int off = 128; off > 0; off >>= 1) {
        if (t < off) sm[t] = fmaxf(sm[t], sm[t + off]);
        __syncthreads();
    }
    mx = sm[0];
    __syncthreads();
    float e[4];
    float sum = 0.f;
#pragma unroll
    for (int i = 0; i < 4; ++i) {
        e[i] = expf(v[i] - mx);
        sum += e[i];
    }
    sm[t] = sum;
    __syncthreads();
    for (int off = 128; off > 0; off >>= 1) {
        if (t < off) sm[t] += sm[t + off];
        __syncthreads();
    }
    float inv = 1.f / sm[0];
#pragma unroll
    for (int i = 0; i < 4; ++i) alpha[(size_t)b * S_ + t + i * 256] = e[i] * inv;
}

// ---------------------------------------------------------------------------
// cbar[b,:] += sum_{s in chunk} alpha[b,s] * context[b,s,:]   (cbar pre-zeroed)
__global__ __launch_bounds__(256) void cbar_k(const float* __restrict__ ctx,
                                              const float* __restrict__ alpha,
                                              float* __restrict__ cbar) {
    const int b = blockIdx.y;
    const int s0 = blockIdx.x * 128;
    const int t = threadIdx.x;
    __shared__ float al[128];
    if (t < 128) al[t] = alpha[(size_t)b * S_ + s0 + t];
    __syncthreads();
    const float2* base = (const float2*)(ctx + ((size_t)b * S_ + s0) * D_);
    float2 c = {0.f, 0.f};
    for (int s = 0; s < 128; ++s) {
        float a = al[s];
        float2 x = base[(size_t)s * (D_ / 2) + t];
        c.x = fmaf(a, x.x, c.x);
        c.y = fmaf(a, x.y, c.y);
    }
    atomicAdd(cbar + (size_t)b * D_ + 2 * t, c.x);
    atomicAdd(cbar + (size_t)b * D_ + 2 * t + 1, c.y);
}

// ---------------------------------------------------------------------------
extern "C" void kernel_launch(void* const* d_in, const int* in_sizes, int n_in,
                              void* d_out, int out_size, void* d_ws, size_t ws_size,
                              hipStream_t stream) {
    const float* input = (const float*)d_in[0];
    const float* ctx   = (const float*)d_in[1];
    const int*   mask  = (const int*)d_in[2];
    const float* W_in  = (const float*)d_in[3];
    const float* b_in  = (const float*)d_in[4];
    const float* W_ctx = (const float*)d_in[5];
    const float* b_ctx = (const float*)d_in[6];
    const float* V     = (const float*)d_in[7];

    float* hidden = (float*)d_out;
    float* alpha  = (float*)d_out + B_ * H_;

    float* inp  = (float*)d_ws;
    float* att  = inp + B_ * H_;
    float* cbar = att + B_ * S_;

    int nz = B_ * S_ + B_ * D_;
    zero_k<<<(nz + 255) / 256, 256, 0, stream>>>(att, nz);

    linear_k<<<(B_ * H_) / 256, 256, 0, stream>>>(input, W_in, b_in, inp);

    dim3 g2(H_ / 128, S_ / 128, B_);
    score_mfma<<<g2, 256, 0, stream>>>(ctx, W_ctx, b_ctx, V, inp, att);

    softmax_k<<<B_, 256, 0, stream>>>(att, mask, alpha);

    dim3 g4(S_ / 128, B_);
    cbar_k<<<g4, 256, 0, stream>>>(ctx, alpha, cbar);

    linear_k<<<(B_ * H_) / 256, 256, 0, stream>>>(cbar, W_ctx, b_ctx, hidden);
}

// Round 3
// 586.824 us; speedup vs baseline: 1.9927x; 1.0642x over previous
//
#include <hip/hip_runtime.h>
#include <math.h>

#define B_ 128
#define S_ 1024
#define D_ 512
#define H_ 512

typedef _Float16 f16x4 __attribute__((ext_vector_type(4)));
typedef _Float16 f16x8 __attribute__((ext_vector_type(8)));
typedef float    f32x4 __attribute__((ext_vector_type(4)));

// ---------------------------------------------------------------------------
__global__ void zero_k(float* __restrict__ p, int n) {
    int i = blockIdx.x * 256 + threadIdx.x;
    if (i < n) p[i] = 0.f;
}

// ---------------------------------------------------------------------------
// out[b,h] = dot(X[b,:], W[h,:]) + bias[h]   (X:[B,D], W:[H,D], D=512)
__global__ __launch_bounds__(256) void linear_k(const float* __restrict__ X,
                                                const float* __restrict__ W,
                                                const float* __restrict__ bias,
                                                float* __restrict__ out) {
    int idx = blockIdx.x * 256 + threadIdx.x;
    int b = idx >> 9;
    int h = idx & 511;
    const float4* x = (const float4*)(X + (size_t)b * D_);
    const float4* w = (const float4*)(W + (size_t)h * D_);
    float s = 0.f;
#pragma unroll 8
    for (int k = 0; k < D_ / 4; ++k) {
        float4 xv = x[k], wv = w[k];
        s = fmaf(xv.x, wv.x, s);
        s = fmaf(xv.y, wv.y, s);
        s = fmaf(xv.z, wv.z, s);
        s = fmaf(xv.w, wv.w, s);
    }
    out[idx] = s + bias[h];
}

// ---------------------------------------------------------------------------
__device__ inline f16x4 cvt4(float4 v) {
    f16x4 r;
    r[0] = (_Float16)v.x; r[1] = (_Float16)v.y;
    r[2] = (_Float16)v.z; r[3] = (_Float16)v.w;
    return r;
}

// fast tanh: 1 - 2/(e^{2x}+1); exact limits at +/-inf
__device__ inline float fast_tanh(float x) {
    float e = __expf(2.f * x);
    return 1.f - 2.f / (e + 1.f);
}

// ---------------------------------------------------------------------------
// Score GEMM, single fp16 MFMA (fp16 precision ample: term std 0.044, K=512).
// Per (h-blk, s-blk, b): 128x128 tile of ctxp[h,s] = W_ctx[h,:]·context[b,s,:]
// Epilogue: att[b,s] += sum_h V[h]*tanh(inp[b,h]+b_ctx[h]+ctxp)  (atomicAdd)
__global__ __launch_bounds__(256) void score_mfma(const float* __restrict__ ctx,
                                                  const float* __restrict__ Wc,
                                                  const float* __restrict__ bc,
                                                  const float* __restrict__ Vv,
                                                  const float* __restrict__ inp,
                                                  float* __restrict__ att) {
    // row-major [row][k] fp16 tiles, stride 40 (80 B) -> 16B-aligned b128 frags
    __shared__ __align__(16) _Float16 Ah[128][40];
    __shared__ __align__(16) _Float16 Bh[128][40];
    __shared__ float red[8][128];

    const int tid = threadIdx.x;
    const int h0 = blockIdx.x * 128;   // h-blk fastest: 4 h-blks share ctx tile in L2
    const int s0 = blockIdx.y * 128;
    const int b  = blockIdx.z;

    // staging: thread covers rows rb+{0,32,64,96}, float4-group grp (k-cols grp*4..+3)
    const int rb  = tid >> 3;   // 0..31
    const int grp = tid & 7;    // 0..7

    const int wave = tid >> 6;
    const int lane = tid & 63;
    const int wm = wave >> 1, wn = wave & 1;   // 2x2 wave grid (h x s)
    const int l15 = lane & 15, quad = lane >> 4;

    const float* Abase = Wc  + (size_t)(h0 + rb) * D_ + grp * 4;
    const float* Bbase = ctx + ((size_t)b * S_ + s0 + rb) * D_ + grp * 4;

    f32x4 acc[4][4];
#pragma unroll
    for (int mi = 0; mi < 4; ++mi)
#pragma unroll
        for (int ni = 0; ni < 4; ++ni) acc[mi][ni] = (f32x4){0.f, 0.f, 0.f, 0.f};

    float4 ra[4], rbv[4];
#pragma unroll
    for (int i = 0; i < 4; ++i) {
        ra[i]  = *(const float4*)(Abase + (size_t)(32 * i) * D_);
        rbv[i] = *(const float4*)(Bbase + (size_t)(32 * i) * D_);
    }

    for (int k0 = 0; k0 < D_; k0 += 32) {
        __syncthreads();   // previous iteration's fragment reads complete
#pragma unroll
        for (int i = 0; i < 4; ++i) {
            const int row = rb + 32 * i;
            *(f16x4*)&Ah[row][grp * 4] = cvt4(ra[i]);
            *(f16x4*)&Bh[row][grp * 4] = cvt4(rbv[i]);
        }
        __syncthreads();
        if (k0 + 32 < D_) {
#pragma unroll
            for (int i = 0; i < 4; ++i) {
                ra[i]  = *(const float4*)(Abase + (size_t)(32 * i) * D_ + k0 + 32);
                rbv[i] = *(const float4*)(Bbase + (size_t)(32 * i) * D_ + k0 + 32);
            }
        }
        // fragments: A[m=l15][k=quad*8+j], B[k=quad*8+j][n=l15]
        f16x8 bhf[4];
#pragma unroll
        for (int ni = 0; ni < 4; ++ni)
            bhf[ni] = *(const f16x8*)&Bh[wn * 64 + ni * 16 + l15][quad * 8];
#pragma unroll
        for (int mi = 0; mi < 4; ++mi) {
            f16x8 ah = *(const f16x8*)&Ah[wm * 64 + mi * 16 + l15][quad * 8];
#pragma unroll
            for (int ni = 0; ni < 4; ++ni)
                acc[mi][ni] = __builtin_amdgcn_mfma_f32_16x16x32_f16(ah, bhf[ni], acc[mi][ni], 0, 0, 0);
        }
    }

    // epilogue: C/D layout col=l15 (s), row=quad*4+reg (h)
    float p[4] = {0.f, 0.f, 0.f, 0.f};
#pragma unroll
    for (int mi = 0; mi < 4; ++mi) {
#pragma unroll
        for (int r = 0; r < 4; ++r) {
            const int h = h0 + wm * 64 + mi * 16 + quad * 4 + r;
            const float c  = inp[(size_t)b * H_ + h] + bc[h];
            const float vh = Vv[h];
#pragma unroll
            for (int ni = 0; ni < 4; ++ni)
                p[ni] = fmaf(vh, fast_tanh(c + acc[mi][ni][r]), p[ni]);
        }
    }
    const int cid = wm * 4 + quad;   // 8 h-contributors per s column
#pragma unroll
    for (int ni = 0; ni < 4; ++ni)
        red[cid][wn * 64 + ni * 16 + l15] = p[ni];
    __syncthreads();
    if (tid < 128) {
        float s = 0.f;
#pragma unroll
        for (int g = 0; g < 8; ++g) s += red[g][tid];
        atomicAdd(att + (size_t)b * S_ + s0 + tid, s);
    }
}

// ---------------------------------------------------------------------------
__global__ __launch_bounds__(256) void softmax_k(const float* __restrict__ att,
                                                 const int* __restrict__ mask,
                                                 float* __restrict__ alpha) {
    const int b = blockIdx.x;
    const int t = threadIdx.x;
    __shared__ float sm[256];
    float v[4];
    float mx = -INFINITY;
#pragma unroll
    for (int i = 0; i < 4; ++i) {
        int s = t + i * 256;
        float a = att[(size_t)b * S_ + s];
        int mk = mask[(size_t)b * S_ + s];
        v[i] = mk ? -INFINITY : a;
        mx = fmaxf(mx, v[i]);
    }
    sm[t] = mx;
    __syncthreads();
    for (int off = 128; off > 0; off >>= 1) {
        if (t < off) sm[t] = fmaxf(sm[t], sm[t + off]);
        __syncthreads();
    }
    mx = sm[0];
    __syncthreads();
    float e[4];
    float sum = 0.f;
#pragma unroll
    for (int i = 0; i < 4; ++i) {
        e[i] = expf(v[i] - mx);
        sum += e[i];
    }
    sm[t] = sum;
    __syncthreads();
    for (int off = 128; off > 0; off >>= 1) {
        if (t < off) sm[t] += sm[t + off];
        __syncthreads();
    }
    float inv = 1.f / sm[0];
#pragma unroll
    for (int i = 0; i < 4; ++i) alpha[(size_t)b * S_ + t + i * 256] = e[i] * inv;
}

// ---------------------------------------------------------------------------
// cbar[b,:] += sum_{s in chunk} alpha[b,s] * context[b,s,:]   (cbar pre-zeroed)
// float4 loads, 2-way s-split, LDS pair-reduce, then atomics (8 contenders).
__global__ __launch_bounds__(256) void cbar_k(const float* __restrict__ ctx,
                                              const float* __restrict__ alpha,
                                              float* __restrict__ cbar) {
    const int b = blockIdx.y;
    const int s0 = blockIdx.x * 128;
    const int t = threadIdx.x;
    const int c4 = t & 127;   // float4 column 0..127 (D/4)
    const int sh = t >> 7;    // 0/1
    __shared__ float al[128];
    __shared__ float4 red[128];
    if (t < 128) al[t] = alpha[(size_t)b * S_ + s0 + t];
    __syncthreads();
    const float4* base = (const float4*)(ctx + ((size_t)b * S_ + s0) * D_);
    float4 c = {0.f, 0.f, 0.f, 0.f};
#pragma unroll 4
    for (int s = sh; s < 128; s += 2) {
        float a = al[s];
        float4 x = base[(size_t)s * (D_ / 4) + c4];
        c.x = fmaf(a, x.x, c.x);
        c.y = fmaf(a, x.y, c.y);
        c.z = fmaf(a, x.z, c.z);
        c.w = fmaf(a, x.w, c.w);
    }
    if (sh == 1) red[c4] = c;
    __syncthreads();
    if (sh == 0) {
        float4 o = red[c4];
        float* dst = cbar + (size_t)b * D_ + c4 * 4;
        atomicAdd(dst + 0, c.x + o.x);
        atomicAdd(dst + 1, c.y + o.y);
        atomicAdd(dst + 2, c.z + o.z);
        atomicAdd(dst + 3, c.w + o.w);
    }
}

// ---------------------------------------------------------------------------
extern "C" void kernel_launch(void* const* d_in, const int* in_sizes, int n_in,
                              void* d_out, int out_size, void* d_ws, size_t ws_size,
                              hipStream_t stream) {
    const float* input = (const float*)d_in[0];
    const float* ctx   = (const float*)d_in[1];
    const int*   mask  = (const int*)d_in[2];
    const float* W_in  = (const float*)d_in[3];
    const float* b_in  = (const float*)d_in[4];
    const float* W_ctx = (const float*)d_in[5];
    const float* b_ctx = (const float*)d_in[6];
    const float* V     = (const float*)d_in[7];

    float* hidden = (float*)d_out;
    float* alpha  = (float*)d_out + B_ * H_;

    float* inp  = (float*)d_ws;
    float* att  = inp + B_ * H_;
    float* cbar = att + B_ * S_;

    int nz = B_ * S_ + B_ * D_;
    zero_k<<<(nz + 255) / 256, 256, 0, stream>>>(att, nz);

    linear_k<<<(B_ * H_) / 256, 256, 0, stream>>>(input, W_in, b_in, inp);

    dim3 g2(H_ / 128, S_ / 128, B_);
    score_mfma<<<g2, 256, 0, stream>>>(ctx, W_ctx, b_ctx, V, inp, att);

    softmax_k<<<B_, 256, 0, stream>>>(att, mask, alpha);

    dim3 g4(S_ / 128, B_);
    cbar_k<<<g4, 256, 0, stream>>>(ctx, alpha, cbar);

    linear_k<<<(B_ * H_) / 256, 256, 0, stream>>>(cbar, W_ctx, b_ctx, hidden);
}